// Round 1
// baseline (272.276 us; speedup 1.0000x reference)
//
#include <hip/hip_runtime.h>
#include <hip/hip_bf16.h>

typedef __bf16 bf16x8 __attribute__((ext_vector_type(8)));
typedef float f32x4 __attribute__((ext_vector_type(4)));
typedef unsigned short ushort_t;

// B=8, P=64, S=512, D=512, L=64
#define NB_ 8
#define PP 64
#define SS 512
#define DD 512
#define LL 64

__device__ __forceinline__ ushort_t f2b(float f) {
    union { float f; unsigned u; } x; x.f = f;
    unsigned r = x.u + 0x7FFFu + ((x.u >> 16) & 1u);
    return (ushort_t)(r >> 16);
}

// ---- shared MFMA GEMM core: C(128 x NF*32) += A(128 x K) @ Bt(NF*32 x K)^T ----
// A rows k-contiguous, Bt rows k-contiguous (B^T form). 256 threads, 4 waves 2x2.
// Fragment layout (verified m89/m91): A/B lane l holds [idx=l&15][k=(l>>4)*8 +0..7],
// C/D: col=lane&15, row=(lane>>4)*4+reg.
template<int NF>
__device__ __forceinline__ void gemm_core(const ushort_t* __restrict__ A, int lda,
                                          const ushort_t* __restrict__ Bt, int ldb,
                                          int K, ushort_t* As, ushort_t* Bs,
                                          f32x4 (&acc)[4][NF]) {
    constexpr int NBLD = (NF == 4) ? 2 : 1;   // B-tile staging passes
    const int tid = threadIdx.x;
    const int lane = tid & 63, wid = tid >> 6;
    const int wr = (wid >> 1) * 64, wc = (wid & 1) * (NF * 16);
    const int r15 = lane & 15, kg = lane >> 4;
    for (int k0 = 0; k0 < K; k0 += 32) {
        uint4 ra[2], rb[NBLD];
#pragma unroll
        for (int i = 0; i < 2; i++) {
            int o = (tid + i * 256) * 16;  // byte offset within [128][32] bf16 tile
            ra[i] = *(const uint4*)(A + (size_t)(o >> 6) * lda + k0 + ((o & 63) >> 1));
        }
#pragma unroll
        for (int i = 0; i < NBLD; i++) {
            int o = (tid + i * 256) * 16;
            rb[i] = *(const uint4*)(Bt + (size_t)(o >> 6) * ldb + k0 + ((o & 63) >> 1));
        }
        __syncthreads();   // previous iter's fragment reads complete
#pragma unroll
        for (int i = 0; i < 2; i++) {
            int o = (tid + i * 256) * 16;
            *(uint4*)(As + (o >> 6) * 32 + ((o & 63) >> 1)) = ra[i];
        }
#pragma unroll
        for (int i = 0; i < NBLD; i++) {
            int o = (tid + i * 256) * 16;
            *(uint4*)(Bs + (o >> 6) * 32 + ((o & 63) >> 1)) = rb[i];
        }
        __syncthreads();   // writes visible
        bf16x8 af[4], bf[NF];
#pragma unroll
        for (int mf = 0; mf < 4; mf++)
            af[mf] = *(const bf16x8*)(As + (wr + mf * 16 + r15) * 32 + kg * 8);
#pragma unroll
        for (int nf = 0; nf < NF; nf++)
            bf[nf] = *(const bf16x8*)(Bs + (wc + nf * 16 + r15) * 32 + kg * 8);
#pragma unroll
        for (int mf = 0; mf < 4; mf++)
#pragma unroll
            for (int nf = 0; nf < NF; nf++)
                acc[mf][nf] = __builtin_amdgcn_mfma_f32_16x16x32_bf16(
                    af[mf], bf[nf], acc[mf][nf], 0, 0, 0);
    }
}

// ---- prep: bf16 conversions, predicate gather, W2 transpose, labels copy ----
__global__ __launch_bounds__(256) void k_prep(
    const float* __restrict__ span, const int* __restrict__ preds,
    const int* __restrict__ labels, const float* __restrict__ Wa,
    const float* __restrict__ Wp, const float* __restrict__ W2,
    ushort_t* spanB, ushort_t* predB, ushort_t* WaB, ushort_t* WpB,
    ushort_t* W2aT, ushort_t* W2bT, float* out) {
    int id = blockIdx.x * 256 + threadIdx.x;
    if (id < 524288) {                       // span -> bf16, 4 elems/thread
        float4 v = ((const float4*)span)[id];
        ((ushort4*)spanB)[id] = make_ushort4(f2b(v.x), f2b(v.y), f2b(v.z), f2b(v.w));
    } else if (id < 589824) {                // predicate gather -> bf16
        int j = id - 524288;
        int row = j >> 7, c4 = j & 127;      // row = b*64+p, 128 float4 per row
        int b = row >> 6;
        int idx = preds[row];
        float4 v = ((const float4*)(span + ((size_t)(b * SS + idx)) * DD))[c4];
        ((ushort4*)(predB + (size_t)row * DD))[c4] =
            make_ushort4(f2b(v.x), f2b(v.y), f2b(v.z), f2b(v.w));
    } else if (id < 851968) {                // labels -> float tail of out
        int k = id - 589824;
        out[16777216 + k] = (float)labels[k];
    } else if (id < 917504) {                // Wa -> bf16
        int j = id - 851968;
        float4 v = ((const float4*)Wa)[j];
        ((ushort4*)WaB)[j] = make_ushort4(f2b(v.x), f2b(v.y), f2b(v.z), f2b(v.w));
    } else if (id < 983040) {                // Wp -> bf16
        int j = id - 917504;
        float4 v = ((const float4*)Wp)[j];
        ((ushort4*)WpB)[j] = make_ushort4(f2b(v.x), f2b(v.y), f2b(v.z), f2b(v.w));
    } else if (id < 1015808) {               // W2aT[l][d] = W2[d][l]
        int j = id - 983040;
        W2aT[j] = f2b(W2[(size_t)(j & 511) * LL + (j >> 9)]);
    } else {                                 // W2bT[l][d] = W2[512+d][l]
        int j = id - 1015808;
        W2bT[j] = f2b(W2[(size_t)((j & 511) + DD) * LL + (j >> 9)]);
    }
}

// ---- W1[l][d][e] f32 -> W1T[l][e][d] bf16 (LDS-tiled transpose) ----
__global__ __launch_bounds__(256) void k_prep_W1T(const float* __restrict__ W1,
                                                  ushort_t* __restrict__ W1T) {
    __shared__ float tile[64][65];
    int l = blockIdx.z, dt = blockIdx.x * 64, et = blockIdx.y * 64;
    int t = threadIdx.x;
    const float* src = W1 + ((size_t)l * DD + dt) * DD + et;
#pragma unroll
    for (int i = 0; i < 16; i++) {
        int dr = (t >> 6) + i * 4, ec = t & 63;
        tile[dr][ec] = src[(size_t)dr * DD + ec];
    }
    __syncthreads();
    ushort_t* dst = W1T + ((size_t)l * DD + et) * DD + dt;
#pragma unroll
    for (int i = 0; i < 8; i++) {
        int er = (t >> 5) + i * 8, d2 = (t & 31) * 2;
        ushort2 v = make_ushort2(f2b(tile[d2][er]), f2b(tile[d2 + 1][er]));
        *(ushort2*)(dst + (size_t)er * DD + d2) = v;
    }
}

// ---- score GEMM: score[m] += sum_n relu(A@Bt^T + bias)[m,n] * w[n] ----
__global__ __launch_bounds__(256) void k_gemm_score(const ushort_t* __restrict__ A,
    const ushort_t* __restrict__ Bt, const float* __restrict__ bias,
    const float* __restrict__ w, float* __restrict__ score) {
    __shared__ ushort_t As[128 * 32], Bs[128 * 32];
    f32x4 acc[4][4];
    const f32x4 z4 = {0.f, 0.f, 0.f, 0.f};
#pragma unroll
    for (int i = 0; i < 4; i++)
#pragma unroll
        for (int j = 0; j < 4; j++) acc[i][j] = z4;
    int m0 = blockIdx.x * 128, n0 = blockIdx.y * 128;
    gemm_core<4>(A + (size_t)m0 * DD, DD, Bt + (size_t)n0 * DD, DD, DD, As, Bs, acc);
    int lane = threadIdx.x & 63, wid = threadIdx.x >> 6;
    int wr = (wid >> 1) * 64, wc = (wid & 1) * 64;
    int r15 = lane & 15, kg = lane >> 4;
#pragma unroll
    for (int mf = 0; mf < 4; mf++)
#pragma unroll
        for (int j = 0; j < 4; j++) {
            float v = 0.f;
#pragma unroll
            for (int nf = 0; nf < 4; nf++) {
                int col = n0 + wc + nf * 16 + r15;
                float c = acc[mf][nf][j] + bias[col];
                if (c > 0.f) v += c * w[col];
            }
            v += __shfl_xor(v, 1); v += __shfl_xor(v, 2);
            v += __shfl_xor(v, 4); v += __shfl_xor(v, 8);
            if (r15 == 0) atomicAdd(&score[m0 + wr + mf * 16 + kg * 4 + j], v);
        }
}

// ---- skinny W2 GEMM: C[m][0..63] = A(Mx512) @ Bt(64x512)^T ----
__global__ __launch_bounds__(256) void k_gemm_w2(const ushort_t* __restrict__ A,
    const ushort_t* __restrict__ Bt, float* __restrict__ C) {
    __shared__ ushort_t As[128 * 32], Bs[64 * 32];
    f32x4 acc[4][2];
    const f32x4 z4 = {0.f, 0.f, 0.f, 0.f};
#pragma unroll
    for (int i = 0; i < 4; i++) { acc[i][0] = z4; acc[i][1] = z4; }
    int m0 = blockIdx.x * 128;
    gemm_core<2>(A + (size_t)m0 * DD, DD, Bt, DD, DD, As, Bs, acc);
    int lane = threadIdx.x & 63, wid = threadIdx.x >> 6;
    int wr = (wid >> 1) * 64, wc = (wid & 1) * 32;
    int r15 = lane & 15, kg = lane >> 4;
#pragma unroll
    for (int mf = 0; mf < 4; mf++)
#pragma unroll
        for (int nf = 0; nf < 2; nf++)
#pragma unroll
            for (int j = 0; j < 4; j++) {
                int m = m0 + wr + mf * 16 + kg * 4 + j;
                int n = wc + nf * 16 + r15;
                C[(size_t)m * LL + n] = acc[mf][nf][j];
            }
}

// ---- U GEMM: UB[(bp*64+l)*512+e] = bf16( pred(512x512) @ W1T[l](512x512)^T ) ----
__global__ __launch_bounds__(256) void k_gemm_U(const ushort_t* __restrict__ predB,
    const ushort_t* __restrict__ W1T, ushort_t* __restrict__ UB) {
    __shared__ ushort_t As[128 * 32], Bs[128 * 32];
    f32x4 acc[4][4];
    const f32x4 z4 = {0.f, 0.f, 0.f, 0.f};
#pragma unroll
    for (int i = 0; i < 4; i++)
#pragma unroll
        for (int j = 0; j < 4; j++) acc[i][j] = z4;
    int m0 = blockIdx.x * 128, n0 = blockIdx.y * 128, l = blockIdx.z;
    gemm_core<4>(predB + (size_t)m0 * DD, DD,
                 W1T + ((size_t)l * DD + n0) * DD, DD, DD, As, Bs, acc);
    int lane = threadIdx.x & 63, wid = threadIdx.x >> 6;
    int wr = (wid >> 1) * 64, wc = (wid & 1) * 64;
    int r15 = lane & 15, kg = lane >> 4;
#pragma unroll
    for (int mf = 0; mf < 4; mf++)
#pragma unroll
        for (int nf = 0; nf < 4; nf++)
#pragma unroll
            for (int j = 0; j < 4; j++) {
                int m = m0 + wr + mf * 16 + kg * 4 + j;
                int n = n0 + wc + nf * 16 + r15;
                UB[((size_t)m * LL + l) * DD + n] = f2b(acc[mf][nf][j]);
            }
}

// ---- final GEMM + fused epilogue ----
__global__ __launch_bounds__(256) void k_gemm_out(const ushort_t* __restrict__ spanB,
    const ushort_t* __restrict__ UB, const float* __restrict__ spanW2,
    const float* __restrict__ predW2, const float* __restrict__ ascore,
    const float* __restrict__ pscore, const float* __restrict__ bias,
    float* __restrict__ out) {
    __shared__ ushort_t As[128 * 32], Bs[64 * 32];
    f32x4 acc[4][2];
    const f32x4 z4 = {0.f, 0.f, 0.f, 0.f};
#pragma unroll
    for (int i = 0; i < 4; i++) { acc[i][0] = z4; acc[i][1] = z4; }
    int m0 = blockIdx.x * 128;
    int bp = blockIdx.y;
    int b = bp >> 6;
    gemm_core<2>(spanB + ((size_t)b * SS + m0) * DD, DD,
                 UB + (size_t)bp * LL * DD, DD, DD, As, Bs, acc);
    int lane = threadIdx.x & 63, wid = threadIdx.x >> 6;
    int wr = (wid >> 1) * 64, wc = (wid & 1) * 32;
    int r15 = lane & 15, kg = lane >> 4;
    float ps = pscore[bp];
#pragma unroll
    for (int mf = 0; mf < 4; mf++)
#pragma unroll
        for (int nf = 0; nf < 2; nf++)
#pragma unroll
            for (int j = 0; j < 4; j++) {
                int s = m0 + wr + mf * 16 + kg * 4 + j;
                int lcol = wc + nf * 16 + r15;
                float v = acc[mf][nf][j] + bias[lcol] + predW2[bp * LL + lcol]
                          + spanW2[((size_t)b * SS + s) * LL + lcol]
                          + ps + ascore[b * SS + s];
                if (lcol == LL - 1) v = 0.f;
                out[((size_t)bp * SS + s) * LL + lcol] = v;
            }
}

extern "C" void kernel_launch(void* const* d_in, const int* in_sizes, int n_in,
                              void* d_out, int out_size, void* d_ws, size_t ws_size,
                              hipStream_t stream) {
    const float* span   = (const float*)d_in[0];
    const int*   preds  = (const int*)d_in[1];
    const int*   labels = (const int*)d_in[2];
    const float* Wp     = (const float*)d_in[4];
    const float* bp_    = (const float*)d_in[5];
    const float* Wa     = (const float*)d_in[6];
    const float* ba_    = (const float*)d_in[7];
    const float* wp     = (const float*)d_in[8];
    const float* wa     = (const float*)d_in[9];
    const float* W1     = (const float*)d_in[10];
    const float* W2     = (const float*)d_in[11];
    const float* bias   = (const float*)d_in[12];
    float* out = (float*)d_out;
    char* ws = (char*)d_ws;

    ushort_t* spanB  = (ushort_t*)(ws + 0);          //  4,194,304
    ushort_t* predB  = (ushort_t*)(ws + 4194304);    //    524,288
    ushort_t* WaB    = (ushort_t*)(ws + 4718592);    //    524,288
    ushort_t* WpB    = (ushort_t*)(ws + 5242880);    //    524,288
    ushort_t* W2aT   = (ushort_t*)(ws + 5767168);    //     65,536
    ushort_t* W2bT   = (ushort_t*)(ws + 5832704);    //     65,536
    ushort_t* W1T    = (ushort_t*)(ws + 5898240);    // 33,554,432
    ushort_t* UB     = (ushort_t*)(ws + 39452672);   // 33,554,432
    float*    ascore = (float*)(ws + 73007104);      //     16,384
    float*    pscore = (float*)(ws + 73023488);      //      2,048
    float*    spanW2 = (float*)(ws + 73025536);      //  1,048,576
    float*    predW2 = (float*)(ws + 74074112);      //    131,072  (total ~74.2 MB)

    hipMemsetAsync(ascore, 0, 16384 + 2048, stream);  // ascore+pscore contiguous

    k_prep<<<4096, 256, 0, stream>>>(span, preds, labels, Wa, Wp, W2,
                                     spanB, predB, WaB, WpB, W2aT, W2bT, out);
    k_prep_W1T<<<dim3(8, 8, 64), 256, 0, stream>>>(W1, W1T);

    k_gemm_score<<<dim3(32, 4), 256, 0, stream>>>(spanB, WaB, ba_, wa, ascore);
    k_gemm_score<<<dim3(4, 4), 256, 0, stream>>>(predB, WpB, bp_, wp, pscore);
    k_gemm_w2<<<32, 256, 0, stream>>>(spanB, W2bT, spanW2);
    k_gemm_w2<<<4, 256, 0, stream>>>(predB, W2aT, predW2);

    k_gemm_U<<<dim3(4, 4, 64), 256, 0, stream>>>(predB, W1T, UB);
    k_gemm_out<<<dim3(4, 512), 256, 0, stream>>>(spanB, UB, spanW2, predW2,
                                                 ascore, pscore, bias, out);
}

// Round 2
// 120.135 us; speedup vs baseline: 2.2664x; 2.2664x over previous
//
#include <hip/hip_runtime.h>
#include <hip/hip_bf16.h>

typedef __bf16 bf16x8 __attribute__((ext_vector_type(8)));
typedef float f32x4 __attribute__((ext_vector_type(4)));
typedef unsigned short ushort_t;

// B=8, P=64, S=512, D=512, L=64
#define SS 512
#define DD 512
#define LL 64

__device__ __forceinline__ ushort_t f2b(float f) {
    union { float f; unsigned u; } x; x.f = f;
    unsigned r = x.u + 0x7FFFu + ((x.u >> 16) & 1u);
    return (ushort_t)(r >> 16);
}

// async global->LDS, 16B per lane; LDS dest must be wave-uniform base + lane*16
__device__ __forceinline__ void async16(const void* g, void* l) {
    __builtin_amdgcn_global_load_lds(
        (const __attribute__((address_space(1))) unsigned int*)g,
        (__attribute__((address_space(3))) unsigned int*)l, 16, 0, 0);
}

// ---- MFMA GEMM core, global_load_lds staging (m97 structure) ----
// C(128 x NF*32) += A(128 x K) @ Bt(NF*32 x K)^T, both operands k-contiguous rows.
// 256 threads = 4 waves (2x2). LDS tiles linear [rows][32] bf16.
// Fragment layout (verified m89/m91): C/D col=lane&15, row=(lane>>4)*4+reg.
template<int NF>
__device__ __forceinline__ void gemm_core(const ushort_t* __restrict__ A, int lda,
                                          const ushort_t* __restrict__ Bt, int ldb,
                                          int K, ushort_t* As, ushort_t* Bs,
                                          f32x4 (&acc)[4][NF]) {
    constexpr int NBLD = (NF == 4) ? 2 : 1;   // B-tile staging passes (8KB or 4KB)
    const int tid = threadIdx.x;
    const int lane = tid & 63, wid = tid >> 6;
    const int wr = (wid >> 1) * 64, wc = (wid & 1) * (NF * 16);
    const int r15 = lane & 15, kg = lane >> 4;
    const int o0 = wid * 1024 + lane * 16;   // byte offset in tile, wave-uniform base + lane*16
    for (int k0 = 0; k0 < K; k0 += 32) {
#pragma unroll
        for (int p = 0; p < 2; p++) {
            int o = o0 + p * 4096;
            async16(A + (size_t)(o >> 6) * lda + k0 + ((o & 63) >> 1), (char*)As + o);
        }
#pragma unroll
        for (int p = 0; p < NBLD; p++) {
            int o = o0 + p * 4096;
            async16(Bt + (size_t)(o >> 6) * ldb + k0 + ((o & 63) >> 1), (char*)Bs + o);
        }
        __syncthreads();   // drains vmcnt: LDS tile ready
        bf16x8 af[4], bf[NF];
#pragma unroll
        for (int mf = 0; mf < 4; mf++)
            af[mf] = *(const bf16x8*)(As + (wr + mf * 16 + r15) * 32 + kg * 8);
#pragma unroll
        for (int nf = 0; nf < NF; nf++)
            bf[nf] = *(const bf16x8*)(Bs + (wc + nf * 16 + r15) * 32 + kg * 8);
#pragma unroll
        for (int mf = 0; mf < 4; mf++)
#pragma unroll
            for (int nf = 0; nf < NF; nf++)
                acc[mf][nf] = __builtin_amdgcn_mfma_f32_16x16x32_bf16(
                    af[mf], bf[nf], acc[mf][nf], 0, 0, 0);
        __syncthreads();   // frag reads done before next overwrite
    }
}

// ---- prep: bf16 conversions, predicate gather, W2 transpose, labels copy ----
__global__ __launch_bounds__(256) void k_prep(
    const float* __restrict__ span, const int* __restrict__ preds,
    const int* __restrict__ labels, const float* __restrict__ Wa,
    const float* __restrict__ Wp, const float* __restrict__ W2,
    ushort_t* spanB, ushort_t* predB, ushort_t* WaB, ushort_t* WpB,
    ushort_t* W2aT, ushort_t* W2bT, float* out) {
    int id = blockIdx.x * 256 + threadIdx.x;
    if (id < 524288) {                       // span -> bf16, 4 elems/thread
        float4 v = ((const float4*)span)[id];
        ((ushort4*)spanB)[id] = make_ushort4(f2b(v.x), f2b(v.y), f2b(v.z), f2b(v.w));
    } else if (id < 589824) {                // predicate gather -> bf16
        int j = id - 524288;
        int row = j >> 7, c4 = j & 127;
        int b = row >> 6;
        int idx = preds[row];
        float4 v = ((const float4*)(span + ((size_t)(b * SS + idx)) * DD))[c4];
        ((ushort4*)(predB + (size_t)row * DD))[c4] =
            make_ushort4(f2b(v.x), f2b(v.y), f2b(v.z), f2b(v.w));
    } else if (id < 851968) {                // labels -> float tail of out
        int k = id - 589824;
        out[16777216 + k] = (float)labels[k];
    } else if (id < 917504) {                // Wa -> bf16
        int j = id - 851968;
        float4 v = ((const float4*)Wa)[j];
        ((ushort4*)WaB)[j] = make_ushort4(f2b(v.x), f2b(v.y), f2b(v.z), f2b(v.w));
    } else if (id < 983040) {                // Wp -> bf16
        int j = id - 917504;
        float4 v = ((const float4*)Wp)[j];
        ((ushort4*)WpB)[j] = make_ushort4(f2b(v.x), f2b(v.y), f2b(v.z), f2b(v.w));
    } else if (id < 1015808) {               // W2aT[l][d] = W2[d][l]
        int j = id - 983040;
        W2aT[j] = f2b(W2[(size_t)(j & 511) * LL + (j >> 9)]);
    } else {                                 // W2bT[l][d] = W2[512+d][l]
        int j = id - 1015808;
        W2bT[j] = f2b(W2[(size_t)((j & 511) + DD) * LL + (j >> 9)]);
    }
}

// ---- W1[l][d][e] f32 -> W1T[l][e][d] bf16 (LDS-tiled transpose) ----
__global__ __launch_bounds__(256) void k_prep_W1T(const float* __restrict__ W1,
                                                  ushort_t* __restrict__ W1T) {
    __shared__ float tile[64][65];
    int l = blockIdx.z, dt = blockIdx.x * 64, et = blockIdx.y * 64;
    int t = threadIdx.x;
    const float* src = W1 + ((size_t)l * DD + dt) * DD + et;
#pragma unroll
    for (int i = 0; i < 16; i++) {
        int dr = (t >> 6) + i * 4, ec = t & 63;
        tile[dr][ec] = src[(size_t)dr * DD + ec];
    }
    __syncthreads();
    ushort_t* dst = W1T + ((size_t)l * DD + et) * DD + dt;
#pragma unroll
    for (int i = 0; i < 8; i++) {
        int er = (t >> 5) + i * 8, d2 = (t & 31) * 2;
        ushort2 v = make_ushort2(f2b(tile[d2][er]), f2b(tile[d2 + 1][er]));
        *(ushort2*)(dst + (size_t)er * DD + d2) = v;
    }
}

// ---- fused small GEMMs: 2 score GEMMs (NF=4) + 2 skinny W2 GEMMs (NF=2) ----
// blocks [0,128): ascore  [128,144): pscore  [144,176): spanW2  [176,180): predW2
__global__ __launch_bounds__(256) void k_small(
    const ushort_t* __restrict__ spanB, const ushort_t* __restrict__ predB,
    const ushort_t* __restrict__ WaB, const ushort_t* __restrict__ WpB,
    const ushort_t* __restrict__ W2bT, const ushort_t* __restrict__ W2aT,
    const float* __restrict__ ba_, const float* __restrict__ bp_,
    const float* __restrict__ wa, const float* __restrict__ wp,
    float* ascore, float* pscore, float* spanW2, float* predW2) {
    __shared__ ushort_t As[128 * 32], Bs[128 * 32];
    const f32x4 z4 = {0.f, 0.f, 0.f, 0.f};
    int blk = blockIdx.x;
    int lane = threadIdx.x & 63, wid = threadIdx.x >> 6;
    int r15 = lane & 15, kg = lane >> 4;
    if (blk < 144) {
        // score path: score[m] += sum_n relu(A@Bt^T + bias)[m,n] * w[n]
        const ushort_t *A, *Bt; const float *bias, *w; float* sc; int m0, n0;
        if (blk < 128) { A = spanB; Bt = WaB; bias = ba_; w = wa; sc = ascore;
                         m0 = (blk >> 2) * 128; n0 = (blk & 3) * 128; }
        else { int q = blk - 128; A = predB; Bt = WpB; bias = bp_; w = wp; sc = pscore;
               m0 = (q >> 2) * 128; n0 = (q & 3) * 128; }
        f32x4 acc[4][4];
#pragma unroll
        for (int i = 0; i < 4; i++)
#pragma unroll
            for (int j = 0; j < 4; j++) acc[i][j] = z4;
        gemm_core<4>(A + (size_t)m0 * DD, DD, Bt + (size_t)n0 * DD, DD, DD, As, Bs, acc);
        int wr = (wid >> 1) * 64, wc = (wid & 1) * 64;
#pragma unroll
        for (int mf = 0; mf < 4; mf++)
#pragma unroll
            for (int j = 0; j < 4; j++) {
                float v = 0.f;
#pragma unroll
                for (int nf = 0; nf < 4; nf++) {
                    int col = n0 + wc + nf * 16 + r15;
                    float c = acc[mf][nf][j] + bias[col];
                    if (c > 0.f) v += c * w[col];
                }
                v += __shfl_xor(v, 1); v += __shfl_xor(v, 2);
                v += __shfl_xor(v, 4); v += __shfl_xor(v, 8);
                if (r15 == 0) atomicAdd(&sc[m0 + wr + mf * 16 + kg * 4 + j], v);
            }
    } else {
        // skinny W2 path: C[m][0..63] = A @ Bt^T
        int q = blk - 144;
        const ushort_t *A, *Bt; float* C; int m0;
        if (q < 32) { A = spanB; Bt = W2bT; C = spanW2; m0 = q * 128; }
        else { A = predB; Bt = W2aT; C = predW2; m0 = (q - 32) * 128; }
        f32x4 acc[4][2];
#pragma unroll
        for (int i = 0; i < 4; i++) { acc[i][0] = z4; acc[i][1] = z4; }
        gemm_core<2>(A + (size_t)m0 * DD, DD, Bt, DD, DD, As, Bs, acc);
        int wr = (wid >> 1) * 64, wc = (wid & 1) * 32;
#pragma unroll
        for (int mf = 0; mf < 4; mf++)
#pragma unroll
            for (int nf = 0; nf < 2; nf++)
#pragma unroll
                for (int j = 0; j < 4; j++) {
                    int m = m0 + wr + mf * 16 + kg * 4 + j;
                    int n = wc + nf * 16 + r15;
                    C[(size_t)m * LL + n] = acc[mf][nf][j];
                }
    }
}

// ---- U GEMM, flat: UB[m*32768 + n] = bf16(pred @ W1T^T), M=512, N=32768, K=512 ----
__global__ __launch_bounds__(256) void k_gemm_U(const ushort_t* __restrict__ predB,
    const ushort_t* __restrict__ W1T, ushort_t* __restrict__ UB) {
    __shared__ ushort_t As[128 * 32], Bs[128 * 32];
    f32x4 acc[4][4];
    const f32x4 z4 = {0.f, 0.f, 0.f, 0.f};
#pragma unroll
    for (int i = 0; i < 4; i++)
#pragma unroll
        for (int j = 0; j < 4; j++) acc[i][j] = z4;
    int m0 = blockIdx.x * 128, n0 = blockIdx.y * 128;
    gemm_core<4>(predB + (size_t)m0 * DD, DD, W1T + (size_t)n0 * DD, DD, DD, As, Bs, acc);
    int lane = threadIdx.x & 63, wid = threadIdx.x >> 6;
    int wr = (wid >> 1) * 64, wc = (wid & 1) * 64;
    int r15 = lane & 15, kg = lane >> 4;
#pragma unroll
    for (int mf = 0; mf < 4; mf++)
#pragma unroll
        for (int nf = 0; nf < 4; nf++)
#pragma unroll
            for (int j = 0; j < 4; j++) {
                int m = m0 + wr + mf * 16 + kg * 4 + j;
                int n = n0 + wc + nf * 16 + r15;
                UB[(size_t)m * 32768 + n] = f2b(acc[mf][nf][j]);
            }
}

// ---- final GEMM + fused epilogue: per b, C[s, p*64+l], M=512, N=4096, K=512 ----
__global__ __launch_bounds__(256) void k_gemm_out(const ushort_t* __restrict__ spanB,
    const ushort_t* __restrict__ UB, const float* __restrict__ spanW2,
    const float* __restrict__ predW2, const float* __restrict__ ascore,
    const float* __restrict__ pscore, const float* __restrict__ bias,
    float* __restrict__ out) {
    __shared__ ushort_t As[128 * 32], Bs[128 * 32];
    f32x4 acc[4][4];
    const f32x4 z4 = {0.f, 0.f, 0.f, 0.f};
#pragma unroll
    for (int i = 0; i < 4; i++)
#pragma unroll
        for (int j = 0; j < 4; j++) acc[i][j] = z4;
    int m0 = blockIdx.x * 128, n0 = blockIdx.y * 128, b = blockIdx.z;
    gemm_core<4>(spanB + ((size_t)b * SS + m0) * DD, DD,
                 UB + ((size_t)b * 4096 + n0) * DD, DD, DD, As, Bs, acc);
    int lane = threadIdx.x & 63, wid = threadIdx.x >> 6;
    int wr = (wid >> 1) * 64, wc = (wid & 1) * 64;
    int r15 = lane & 15, kg = lane >> 4;
    // per-column constants (depend only on n)
    float cn[4]; int nn[4];
#pragma unroll
    for (int nf = 0; nf < 4; nf++) {
        int n = n0 + wc + nf * 16 + r15;
        nn[nf] = n;
        cn[nf] = bias[n & 63] + predW2[b * 4096 + n] + pscore[b * 64 + (n >> 6)];
    }
#pragma unroll
    for (int mf = 0; mf < 4; mf++)
#pragma unroll
        for (int j = 0; j < 4; j++) {
            int s = m0 + wr + mf * 16 + kg * 4 + j;
            float as_ = ascore[b * SS + s];
            const float* sw = spanW2 + ((size_t)b * SS + s) * LL;
#pragma unroll
            for (int nf = 0; nf < 4; nf++) {
                int n = nn[nf], l = n & 63, p = n >> 6;
                float v = acc[mf][nf][j] + cn[nf] + as_ + sw[l];
                if (l == LL - 1) v = 0.f;
                out[(((size_t)b * 64 + p) * SS + s) * LL + l] = v;
            }
        }
}

extern "C" void kernel_launch(void* const* d_in, const int* in_sizes, int n_in,
                              void* d_out, int out_size, void* d_ws, size_t ws_size,
                              hipStream_t stream) {
    const float* span   = (const float*)d_in[0];
    const int*   preds  = (const int*)d_in[1];
    const int*   labels = (const int*)d_in[2];
    const float* Wp     = (const float*)d_in[4];
    const float* bp_    = (const float*)d_in[5];
    const float* Wa     = (const float*)d_in[6];
    const float* ba_    = (const float*)d_in[7];
    const float* wp     = (const float*)d_in[8];
    const float* wa     = (const float*)d_in[9];
    const float* W1     = (const float*)d_in[10];
    const float* W2     = (const float*)d_in[11];
    const float* bias   = (const float*)d_in[12];
    float* out = (float*)d_out;
    char* ws = (char*)d_ws;

    ushort_t* spanB  = (ushort_t*)(ws + 0);          //  4,194,304
    ushort_t* predB  = (ushort_t*)(ws + 4194304);    //    524,288
    ushort_t* WaB    = (ushort_t*)(ws + 4718592);    //    524,288
    ushort_t* WpB    = (ushort_t*)(ws + 5242880);    //    524,288
    ushort_t* W2aT   = (ushort_t*)(ws + 5767168);    //     65,536
    ushort_t* W2bT   = (ushort_t*)(ws + 5832704);    //     65,536
    ushort_t* W1T    = (ushort_t*)(ws + 5898240);    // 33,554,432
    ushort_t* UB     = (ushort_t*)(ws + 39452672);   // 33,554,432
    float*    ascore = (float*)(ws + 73007104);      //     16,384
    float*    pscore = (float*)(ws + 73023488);      //      2,048
    float*    spanW2 = (float*)(ws + 73025536);      //  1,048,576
    float*    predW2 = (float*)(ws + 74074112);      //    131,072  (total ~74.2 MB)

    hipMemsetAsync(ascore, 0, 16384 + 2048, stream);  // ascore+pscore contiguous

    k_prep<<<4096, 256, 0, stream>>>(span, preds, labels, Wa, Wp, W2,
                                     spanB, predB, WaB, WpB, W2aT, W2bT, out);
    k_prep_W1T<<<dim3(8, 8, 64), 256, 0, stream>>>(W1, W1T);

    k_small<<<180, 256, 0, stream>>>(spanB, predB, WaB, WpB, W2bT, W2aT,
                                     ba_, bp_, wa, wp, ascore, pscore, spanW2, predW2);

    k_gemm_U<<<dim3(4, 256), 256, 0, stream>>>(predB, W1T, UB);
    k_gemm_out<<<dim3(4, 32, 8), 256, 0, stream>>>(spanB, UB, spanW2, predW2,
                                                   ascore, pscore, bias, out);
}